// Round 1
// baseline (1739.120 us; speedup 1.0000x reference)
//
#include <hip/hip_runtime.h>
#include <hip/hip_bf16.h>

#define NPT   16384
#define NBAT  16
#define CH    288
#define SP    256
#define KS    16
#define LD    65536           // NBAT*SP*KS columns
#define OFF_FEAT 12288L       // new_xyz = 16*256*3 elements
#define OFF_IND  1191936L     // + new_features 16*288*256

// ---------- helpers ----------
__device__ __forceinline__ float bfbits(unsigned short u){
  unsigned int x = ((unsigned int)u) << 16; float f; __builtin_memcpy(&f,&x,4); return f;
}
__device__ __forceinline__ float bflo(unsigned int w){ unsigned int x = w<<16;          float f; __builtin_memcpy(&f,&x,4); return f; }
__device__ __forceinline__ float bfhi(unsigned int w){ unsigned int x = w&0xffff0000u; float f; __builtin_memcpy(&f,&x,4); return f; }

// dtype-flag branched load/store (flag uniform -> scalar branch)
__device__ __forceinline__ float ldf(const void* p, long i, int isb){
  if (isb) return __bfloat162float(((const __hip_bfloat16*)p)[i]);
  return ((const float*)p)[i];
}
__device__ __forceinline__ void sto(void* p, long i, float v, int isb){
  if (isb) ((__hip_bfloat16*)p)[i] = __float2bfloat16(v);
  else     ((float*)p)[i] = v;
}

// ---------- 0. input dtype detection ----------
// Interpret first 4096 halves of xyz as bf16. True bf16 xyz: all values in [0,1].
// f32-underneath: low halves have random exponent bits -> values >= 4 (or inf/nan)
// appear with certainty.
__global__ void detect_k(const void* __restrict__ xyz, int* __restrict__ flag){
  __shared__ float red[256];
  const int t = threadIdx.x;
  const unsigned short* u = (const unsigned short*)xyz;
  float m = 0.f;
  for (int i = t; i < 4096; i += 256){
    float f = fabsf(bfbits(u[i]));
    if (f != f) f = 1e30f;          // NaN -> huge
    m = fmaxf(m, f);
  }
  red[t] = m; __syncthreads();
  for (int s = 128; s; s >>= 1){ if (t < s) red[t] = fmaxf(red[t], red[t+s]); __syncthreads(); }
  if (t == 0) *flag = (red[0] < 2.0f) ? 1 : 0;   // 1 = bf16, 0 = f32
}

// ---------- 1. farthest point sampling ----------
// One block per batch; 1024 threads hold 16 points each in registers.
// Must bit-match numpy f32: no FMA contraction, (dx*dx+dy*dy)+dz*dz order,
// argmax tie-break = lowest index.
__global__ __launch_bounds__(1024) void fps_k(const void* __restrict__ xyz,
    const int* __restrict__ flag, float* __restrict__ nxyz, void* __restrict__ dout){
  #pragma clang fp contract(off)
  const int b = blockIdx.x, t = threadIdx.x;
  const int isb = *flag;
  const long base = (long)b*NPT*3;
  float px[16], py[16], pz[16], dist[16];
  #pragma unroll
  for (int i=0;i<16;i++){
    const long id = t + i*1024;
    px[i] = ldf(xyz, base+id*3+0, isb);
    py[i] = ldf(xyz, base+id*3+1, isb);
    pz[i] = ldf(xyz, base+id*3+2, isb);
    dist[i] = 1e10f;
  }
  __shared__ float rv[16]; __shared__ int ri[16]; __shared__ int scur;
  int cur = 0;
  for (int it=0; it<SP; it++){
    const float cx = ldf(xyz, base+(long)cur*3+0, isb);
    const float cy = ldf(xyz, base+(long)cur*3+1, isb);
    const float cz = ldf(xyz, base+(long)cur*3+2, isb);
    if (t == 0){
      const long bs = (long)b*SP + it;
      nxyz[bs*3+0] = cx; nxyz[bs*3+1] = cy; nxyz[bs*3+2] = cz;
      sto(dout, bs*3+0, cx, isb);
      sto(dout, bs*3+1, cy, isb);
      sto(dout, bs*3+2, cz, isb);
      sto(dout, OFF_IND + bs, (float)cur, isb);
    }
    float bv = -1.f; int bi = 0;
    #pragma unroll
    for (int i=0;i<16;i++){
      float dx = px[i]-cx, dy = py[i]-cy, dz = pz[i]-cz;
      float d2 = dx*dx + dy*dy; d2 = d2 + dz*dz;
      float dn = fminf(dist[i], d2); dist[i] = dn;
      if (dn > bv){ bv = dn; bi = t + i*1024; }   // i ascending -> earliest idx kept
    }
    #pragma unroll
    for (int off=32; off; off>>=1){
      float ov = __shfl_down(bv, off, 64);
      int   oi = __shfl_down(bi, off, 64);
      if (ov > bv || (ov == bv && oi < bi)){ bv = ov; bi = oi; }
    }
    if ((t & 63) == 0){ rv[t>>6] = bv; ri[t>>6] = bi; }
    __syncthreads();
    if (t == 0){
      float gv = rv[0]; int gi = ri[0];
      #pragma unroll
      for (int w=1; w<16; w++)
        if (rv[w] > gv || (rv[w] == gv && ri[w] < gi)){ gv = rv[w]; gi = ri[w]; }
      scur = gi;
    }
    __syncthreads();
    cur = scur;
  }
}

// ---------- 2. ball query ----------
// One wave per (b,s): scan points in index order with ballot, take first 16
// in-radius, pad with first found. Early exit once 16 found.
__global__ __launch_bounds__(256) void ballq_k(const void* __restrict__ xyz,
    const int* __restrict__ flag, const float* __restrict__ nxyz, int* __restrict__ bidx){
  #pragma clang fp contract(off)
  const int isb = *flag;
  const int gw = (blockIdx.x*blockDim.x + threadIdx.x) >> 6;
  const int lane = threadIdx.x & 63;
  const int b = gw >> 8;
  const long base = (long)b*NPT*3;
  const float cx = nxyz[gw*3+0], cy = nxyz[gw*3+1], cz = nxyz[gw*3+2];
  int cnt = 0, first = 0; bool havef = false;
  for (int st = 0; st < NPT && cnt < KS; st += 64){
    const long id = st + lane;
    float dx = ldf(xyz, base+id*3+0, isb) - cx;
    float dy = ldf(xyz, base+id*3+1, isb) - cy;
    float dz = ldf(xyz, base+id*3+2, isb) - cz;
    float d2 = dx*dx + dy*dy; d2 = d2 + dz*dz;
    unsigned long long mk = __ballot(d2 < 0.09f);
    if (mk){
      if (!havef){ first = st + __builtin_ctzll(mk); havef = true; }
      int rank = cnt + __popcll(mk & ((1ull<<lane)-1ull));
      if (((mk>>lane)&1ull) && rank < KS) bidx[gw*KS + rank] = (int)id;
      cnt += __popcll(mk);
    }
  }
  if (cnt < KS && lane >= cnt && lane < KS) bidx[gw*KS + lane] = first;
}

// ---------- 3. gather + concat -> h0 (bf16, 304 x 65536, rows 291..303 zero) ----------
__global__ __launch_bounds__(256) void gather_k(const void* __restrict__ xyz,
    const void* __restrict__ feat, const int* __restrict__ flag,
    const int* __restrict__ bidx, const float* __restrict__ nxyz,
    __hip_bfloat16* __restrict__ h0){
  const int isb = *flag;
  const int n = blockIdx.x*256 + threadIdx.x;   // n = b*4096 + s*16 + k
  const int c = blockIdx.y;                     // 0..303
  float v = 0.f;
  if (c < 291){
    const int id = bidx[n];
    const int b = n >> 12;
    if (c < 3){
      v = (ldf(xyz, ((long)b*NPT + id)*3 + c, isb) - nxyz[(n>>4)*3 + c]) / 0.3f;
    } else {
      v = ldf(feat, ((long)b*CH + (c-3))*(long)NPT + id, isb);
    }
  }
  h0[(long)c*LD + n] = __float2bfloat16(v);
}

// ---------- 4. GEMM (288 x K) @ (K x 65536) + BN + ReLU -> bf16 ----------
// Block tile 64x128, BK=16, 256 threads, 4x8 microtile, fp32 accumulate.
__global__ __launch_bounds__(256) void gemm_k(const void* __restrict__ W,
    const void* __restrict__ gg, const void* __restrict__ bb,
    const void* __restrict__ mm, const void* __restrict__ vv,
    const int* __restrict__ flag,
    const __hip_bfloat16* __restrict__ Bin, __hip_bfloat16* __restrict__ Out,
    int K, int Kpad){
  const int isb = *flag;
  __shared__ float As[16][64];    // [k][m]
  __shared__ float Bs[16][128];   // [k][n]
  const int t = threadIdx.x;
  const int bx = blockIdx.x, by = blockIdx.y;
  const int tm = t >> 4, tn = t & 15;
  const int ar = t >> 2, ac = (t & 3) << 2;
  const int br = t >> 4, bc = tn << 3;
  const int row0 = by << 6;
  float acc[4][8];
  #pragma unroll
  for (int i=0;i<4;i++)
    #pragma unroll
    for (int j=0;j<8;j++) acc[i][j] = 0.f;

  for (int kt = 0; kt < Kpad; kt += 16){
    #pragma unroll
    for (int j=0;j<4;j++){
      int r = row0 + ar, c = kt + ac + j;
      As[ac+j][ar] = (r < CH && c < K) ? ldf(W, (long)r*K + c, isb) : 0.f;
    }
    {
      const __hip_bfloat16* src = Bin + (long)(kt+br)*LD + (bx<<7) + bc;
      uint4 u = *(const uint4*)src;                       // 8 bf16
      *(float4*)&Bs[br][bc]   = make_float4(bflo(u.x), bfhi(u.x), bflo(u.y), bfhi(u.y));
      *(float4*)&Bs[br][bc+4] = make_float4(bflo(u.z), bfhi(u.z), bflo(u.w), bfhi(u.w));
    }
    __syncthreads();
    #pragma unroll
    for (int kk=0; kk<16; kk++){
      float4 a  = *(const float4*)&As[kk][tm<<2];
      float4 b0 = *(const float4*)&Bs[kk][tn<<3];
      float4 b1 = *(const float4*)&Bs[kk][(tn<<3)+4];
      float av[4]  = {a.x, a.y, a.z, a.w};
      float bv8[8] = {b0.x,b0.y,b0.z,b0.w,b1.x,b1.y,b1.z,b1.w};
      #pragma unroll
      for (int i=0;i<4;i++)
        #pragma unroll
        for (int j=0;j<8;j++) acc[i][j] += av[i]*bv8[j];
    }
    __syncthreads();
  }
  #pragma unroll
  for (int i=0;i<4;i++){
    int o = row0 + (tm<<2) + i;
    if (o < CH){
      float sc = ldf(gg,o,isb) * rsqrtf(ldf(vv,o,isb) + 1e-5f);
      float mu = ldf(mm,o,isb), bi_ = ldf(bb,o,isb);
      long ob = (long)o*LD + (bx<<7) + (tn<<3);
      #pragma unroll
      for (int j=0;j<8;j++){
        float r = (acc[i][j] - mu)*sc + bi_;
        Out[ob+j] = __float2bfloat16(fmaxf(r, 0.f));
      }
    }
  }
}

// ---------- 5. max over k (16 consecutive cols) -> new_features ----------
__global__ __launch_bounds__(256) void maxk_k(const __hip_bfloat16* __restrict__ h,
    const int* __restrict__ flag, void* __restrict__ dout){
  const int isb = *flag;
  const int e = blockIdx.x*256 + threadIdx.x;     // e = b*73728 + o*256 + s
  const int s = e & 255;
  const int o = (e >> 8) % CH;
  const int b = e / (CH*SP);
  const uint4* p = (const uint4*)(h + (long)o*LD + b*4096 + s*16);
  uint4 u0 = p[0], u1 = p[1];
  unsigned int w8[8] = {u0.x,u0.y,u0.z,u0.w,u1.x,u1.y,u1.z,u1.w};
  float m = -1e30f;
  #pragma unroll
  for (int i=0;i<8;i++){ m = fmaxf(m, bflo(w8[i])); m = fmaxf(m, bfhi(w8[i])); }
  sto(dout, OFF_FEAT + e, m, isb);
}

extern "C" void kernel_launch(void* const* d_in, const int* in_sizes, int n_in,
                              void* d_out, int out_size, void* d_ws, size_t ws_size,
                              hipStream_t stream){
  const void* xyz  = d_in[0];
  const void* feat = d_in[1];
  const void* W0 = d_in[2];  const void* g0 = d_in[3];  const void* b0 = d_in[4];
  const void* m0 = d_in[5];  const void* v0 = d_in[6];
  const void* W1 = d_in[7];  const void* g1 = d_in[8];  const void* b1 = d_in[9];
  const void* m1 = d_in[10]; const void* v1 = d_in[11];
  const void* W2 = d_in[12]; const void* g2 = d_in[13]; const void* b2 = d_in[14];
  const void* m2 = d_in[15]; const void* v2 = d_in[16];

  char* ws = (char*)d_ws;
  int*   flag = (int*)ws;                                 // [0,4)
  float* nxyz = (float*)(ws + 256);                       // 16*256*3 f32 = 48KB
  int*   bidx = (int*)(ws + 65536);                       // 65536 i32 = 256KB
  __hip_bfloat16* h0 = (__hip_bfloat16*)(ws + 524288);    // 304*65536 bf16 = 39.85MB
  __hip_bfloat16* h1 = (__hip_bfloat16*)(ws + 40370176);  // 288*65536 bf16 = 37.75MB
  // total ws use ~78.1 MB

  detect_k<<<1, 256, 0, stream>>>(xyz, flag);
  fps_k<<<NBAT, 1024, 0, stream>>>(xyz, flag, nxyz, d_out);
  ballq_k<<<1024, 256, 0, stream>>>(xyz, flag, nxyz, bidx);
  gather_k<<<dim3(256, 304), 256, 0, stream>>>(xyz, feat, flag, bidx, nxyz, h0);
  // L0: h1 = relu(bn(W0 @ h0)), K=291 padded to 304
  gemm_k<<<dim3(512, 5), 256, 0, stream>>>(W0, g0, b0, m0, v0, flag, h0, h1, 291, 304);
  // L1: h0 = relu(bn(W1 @ h1)), K=288
  gemm_k<<<dim3(512, 5), 256, 0, stream>>>(W1, g1, b1, m1, v1, flag, h1, h0, 288, 288);
  // L2: h1 = relu(bn(W2 @ h0)), K=288
  gemm_k<<<dim3(512, 5), 256, 0, stream>>>(W2, g2, b2, m2, v2, flag, h0, h1, 288, 288);
  maxk_k<<<4608, 256, 0, stream>>>(h1, flag, d_out);
}

// Round 2
// 1268.799 us; speedup vs baseline: 1.3707x; 1.3707x over previous
//
#include <hip/hip_runtime.h>
#include <hip/hip_bf16.h>
#include <string.h>

#define NPT   16384
#define NBAT  16
#define CH    288
#define SP    256
#define KS    16
#define OFF_FEAT 12288L
#define OFF_IND  1191936L

// ---------- helpers ----------
__device__ __forceinline__ float bfbits(unsigned short u){
  unsigned int x = ((unsigned int)u) << 16; float f; __builtin_memcpy(&f,&x,4); return f;
}
__device__ __forceinline__ float ldf(const void* p, long i, int isb){
  if (isb) return __bfloat162float(((const __hip_bfloat16*)p)[i]);
  return ((const float*)p)[i];
}
__device__ __forceinline__ void sto(void* p, long i, float v, int isb){
  if (isb) ((__hip_bfloat16*)p)[i] = __float2bfloat16(v);
  else     ((float*)p)[i] = v;
}
__device__ __forceinline__ void gload_lds(const void* g, void* l){
  __builtin_amdgcn_global_load_lds((const __attribute__((address_space(1))) void*)g,
      (__attribute__((address_space(3))) void*)l, 16, 0, 0);
}

typedef __attribute__((ext_vector_type(8))) short bf16x8;
typedef __attribute__((ext_vector_type(4))) float f32x4;

// ---------- 0. input dtype detection ----------
__global__ void detect_k(const void* __restrict__ xyz, int* __restrict__ flag){
  __shared__ float red[256];
  const int t = threadIdx.x;
  const unsigned short* u = (const unsigned short*)xyz;
  float m = 0.f;
  for (int i = t; i < 4096; i += 256){
    float f = fabsf(bfbits(u[i]));
    if (f != f) f = 1e30f;
    m = fmaxf(m, f);
  }
  red[t] = m; __syncthreads();
  for (int s = 128; s; s >>= 1){ if (t < s) red[t] = fmaxf(red[t], red[t+s]); __syncthreads(); }
  if (t == 0) *flag = (red[0] < 2.0f) ? 1 : 0;
}

// ---------- 0b. xyz -> f32 SoA ----------
__global__ __launch_bounds__(256) void cvtxyz_k(const void* __restrict__ xyz,
    const int* __restrict__ flag, float* __restrict__ X, float* __restrict__ Y,
    float* __restrict__ Z){
  const int e = blockIdx.x*256 + threadIdx.x;       // < 786432
  const int isb = *flag;
  float v = ldf(xyz, e, isb);
  int b = e / (NPT*3), r = e - b*(NPT*3), i = r/3, c = r - i*3;
  float* P = (c==0) ? X : ((c==1) ? Y : Z);
  P[b*NPT + i] = v;
}

// ---------- 0c. W -> bf16 [288][296] + BN scale/shift ----------
__global__ __launch_bounds__(256) void cvtw_k(const void* __restrict__ W,
    const void* __restrict__ g, const void* __restrict__ bb,
    const void* __restrict__ m, const void* __restrict__ v,
    const int* __restrict__ flag, __hip_bfloat16* __restrict__ Wbf,
    float* __restrict__ scale, float* __restrict__ shift, int Kin){
  const int isb = *flag;
  const int idx = blockIdx.x*256 + threadIdx.x;
  if (idx < 288*296){
    int o = idx / 296, k = idx - o*296;
    float val = (k < Kin) ? ldf(W, (long)o*Kin + k, isb) : 0.f;
    Wbf[idx] = __float2bfloat16(val);
  }
  if (idx < 288){
    float sc = ldf(g, idx, isb) * rsqrtf(ldf(v, idx, isb) + 1e-5f);
    scale[idx] = sc;
    shift[idx] = ldf(bb, idx, isb) - ldf(m, idx, isb)*sc;
  }
}

// ---------- 1. FPS: 512 thr x 32 pts in registers, coords carried in reduction ----------
__global__ __launch_bounds__(512, 2) void fps_k(const float* __restrict__ X,
    const float* __restrict__ Y, const float* __restrict__ Z,
    const int* __restrict__ flag, float* __restrict__ nxyz, void* __restrict__ dout){
  #pragma clang fp contract(off)
  const int b = blockIdx.x, t = threadIdx.x;
  const int isb = *flag;
  const int base = b*NPT;
  float px[32], py[32], pz[32], dist[32];
  #pragma unroll
  for (int i=0;i<32;i++){
    px[i] = X[base + t + i*512];
    py[i] = Y[base + t + i*512];
    pz[i] = Z[base + t + i*512];
    dist[i] = 1e10f;
  }
  __shared__ float rv[8], rx[8], ry[8], rz[8];
  __shared__ int ri[8];
  __shared__ float scx, scy, scz; __shared__ int scur;
  float cx = X[base], cy = Y[base], cz = Z[base];
  int cur = 0;
  for (int it=0; it<SP; it++){
    if (t == 0){
      const long bs = (long)b*SP + it;
      nxyz[bs*3+0] = cx; nxyz[bs*3+1] = cy; nxyz[bs*3+2] = cz;
      sto(dout, bs*3+0, cx, isb);
      sto(dout, bs*3+1, cy, isb);
      sto(dout, bs*3+2, cz, isb);
      sto(dout, OFF_IND + bs, (float)cur, isb);
    }
    float bv = -1.f, bx_ = 0.f, by_ = 0.f, bz_ = 0.f; int bi = 0;
    #pragma unroll
    for (int i=0;i<32;i++){
      float dx = px[i]-cx, dy = py[i]-cy, dz = pz[i]-cz;
      float d2 = dx*dx + dy*dy; d2 = d2 + dz*dz;
      float dn = fminf(dist[i], d2); dist[i] = dn;
      if (dn > bv){ bv = dn; bi = t + i*512; bx_ = px[i]; by_ = py[i]; bz_ = pz[i]; }
    }
    #pragma unroll
    for (int off=32; off; off>>=1){
      float ov = __shfl_down(bv, off, 64);
      int   oi = __shfl_down(bi, off, 64);
      float ox = __shfl_down(bx_, off, 64);
      float oy = __shfl_down(by_, off, 64);
      float oz = __shfl_down(bz_, off, 64);
      if (ov > bv || (ov == bv && oi < bi)){ bv=ov; bi=oi; bx_=ox; by_=oy; bz_=oz; }
    }
    if ((t & 63) == 0){ int w = t>>6; rv[w]=bv; ri[w]=bi; rx[w]=bx_; ry[w]=by_; rz[w]=bz_; }
    __syncthreads();
    if (t == 0){
      float gv = rv[0]; int gi = ri[0]; float gx=rx[0], gy=ry[0], gz=rz[0];
      #pragma unroll
      for (int w=1; w<8; w++)
        if (rv[w] > gv || (rv[w] == gv && ri[w] < gi)){ gv=rv[w]; gi=ri[w]; gx=rx[w]; gy=ry[w]; gz=rz[w]; }
      scur = gi; scx = gx; scy = gy; scz = gz;
    }
    __syncthreads();
    cur = scur; cx = scx; cy = scy; cz = scz;
  }
}

// ---------- 2. ball query (SoA f32) ----------
__global__ __launch_bounds__(256) void ballq_k(const float* __restrict__ X,
    const float* __restrict__ Y, const float* __restrict__ Z,
    const float* __restrict__ nxyz, int* __restrict__ bidx){
  #pragma clang fp contract(off)
  const int gw = (blockIdx.x*256 + threadIdx.x) >> 6;
  const int lane = threadIdx.x & 63;
  const int b = gw >> 8, base = b*NPT;
  const float cx = nxyz[gw*3+0], cy = nxyz[gw*3+1], cz = nxyz[gw*3+2];
  int cnt = 0, first = 0; bool havef = false;
  for (int st = 0; st < NPT && cnt < KS; st += 64){
    const int id = st + lane;
    float dx = X[base+id]-cx, dy = Y[base+id]-cy, dz = Z[base+id]-cz;
    float d2 = dx*dx + dy*dy; d2 = d2 + dz*dz;
    unsigned long long mk = __ballot(d2 <= 0.09f);  // == (f32 d2 < double 0.09)
    if (mk){
      if (!havef){ first = st + __builtin_ctzll(mk); havef = true; }
      int rank = cnt + __popcll(mk & ((1ull<<lane)-1ull));
      if (((mk>>lane)&1ull) && rank < KS) bidx[gw*KS + rank] = id;
      cnt += __popcll(mk);
    }
  }
  if (cnt < KS && lane >= cnt && lane < KS) bidx[gw*KS + lane] = first;
}

// ---------- 3. gather -> h0 [n][296] bf16 via LDS tile ----------
__global__ __launch_bounds__(256) void gather_k(const void* __restrict__ xyz,
    const void* __restrict__ feat, const int* __restrict__ flag,
    const int* __restrict__ bidx, const float* __restrict__ nxyz,
    __hip_bfloat16* __restrict__ h0){
  __shared__ __hip_bfloat16 tile[64*296];
  const int isb = *flag;
  const int t = threadIdx.x, n0 = blockIdx.x*64;
  const int nl = t >> 2, cg = t & 3;
  const int n = n0 + nl, b = n >> 12, s = n >> 4;
  const int id = bidx[n];
  for (int j=0; j<74; j++){
    int c = cg*74 + j;
    float vv = 0.f;
    if (c < 3)       vv = (ldf(xyz, ((long)b*NPT + id)*3 + c, isb) - nxyz[(long)s*3 + c]) / 0.3f;
    else if (c < 291) vv = ldf(feat, ((long)b*CH + (c-3))*(long)NPT + id, isb);
    tile[nl*296 + c] = __float2bfloat16(vv);
  }
  __syncthreads();
  const uint4* src = (const uint4*)tile;
  uint4* dst = (uint4*)((char*)h0 + (long)n0*592);
  for (int j = t; j < 2368; j += 256) dst[j] = src[j];
}

// ---------- 4. MFMA GEMM: Out[n][o] = relu(BN(sum_k A[n][k]*W[o][k])) ----------
// Block tile 128n x 96o, whole-K A-tile in LDS (global_load_lds), W frags from L2.
__global__ __launch_bounds__(256, 2) void gemm_k(
    const __hip_bfloat16* __restrict__ A, int astr,
    const __hip_bfloat16* __restrict__ W,
    const float* __restrict__ scale, const float* __restrict__ shift,
    __hip_bfloat16* __restrict__ Out, int ostr,
    int ktiles, int kvalid){
  extern __shared__ char lds[];
  const int t = threadIdx.x, lane = t & 63, wid = t >> 6;
  const int wm = wid & 1, wo = wid >> 1;
  const int bx = blockIdx.x, by = blockIdx.y;
  {
    const char* src = (const char*)(A + (long)bx*128*astr);
    const int chunks = (128*astr*2) >> 10;
    for (int c = wid; c < chunks; c += 4)
      gload_lds(src + c*1024 + lane*16, lds + c*1024);
  }
  f32x4 acc[4][3];
  #pragma unroll
  for (int mf=0; mf<4; mf++)
    #pragma unroll
    for (int of=0; of<3; of++) acc[mf][of] = (f32x4){0.f,0.f,0.f,0.f};

  const int mrow  = wm*64 + (lane & 15);
  const int kg    = (lane >> 4) * 8;
  const int obase = by*96 + wo*48 + (lane & 15);
  __syncthreads();

  for (int kt = 0; kt < ktiles; kt++){
    const int k0 = kt*32 + kg;
    const bool z = (k0 >= kvalid);
    const int k0c = z ? 0 : k0;
    bf16x8 a[4], bf[3];
    #pragma unroll
    for (int mf=0; mf<4; mf++)
      a[mf] = *(const bf16x8*)(lds + ((long)(mrow + mf*16)*astr + k0c)*2);
    if (z){
      bf16x8 zz = {0,0,0,0,0,0,0,0};
      #pragma unroll
      for (int mf=0; mf<4; mf++) a[mf] = zz;
    }
    #pragma unroll
    for (int of=0; of<3; of++)
      bf[of] = *(const bf16x8*)(W + (long)(obase + of*16)*296 + k0c);
    #pragma unroll
    for (int mf=0; mf<4; mf++)
      #pragma unroll
      for (int of=0; of<3; of++)
        acc[mf][of] = __builtin_amdgcn_mfma_f32_16x16x32_bf16(a[mf], bf[of], acc[mf][of], 0, 0, 0);
  }

  float sc[3], sh[3];
  #pragma unroll
  for (int of=0; of<3; of++){ sc[of] = scale[obase + of*16]; sh[of] = shift[obase + of*16]; }
  #pragma unroll
  for (int mf=0; mf<4; mf++)
    #pragma unroll
    for (int of=0; of<3; of++)
      #pragma unroll
      for (int r=0; r<4; r++){
        const long row = (long)bx*128 + wm*64 + mf*16 + (lane>>4)*4 + r;
        const int o = obase + of*16;
        float vv = acc[mf][of][r]*sc[of] + sh[of];
        Out[row*ostr + o] = __float2bfloat16(fmaxf(vv, 0.f));
      }
}

// ---------- 5. maxpool over k: h[n][288] -> out[b][o][s] ----------
__global__ __launch_bounds__(256) void maxk_k(const __hip_bfloat16* __restrict__ h,
    const int* __restrict__ flag, void* __restrict__ dout){
  __shared__ __hip_bfloat16 tile[128*288];
  const int isb = *flag;
  const int t = threadIdx.x;
  const int b = blockIdx.x >> 5, s0 = (blockIdx.x & 31)*8;
  const long n0 = (long)b*4096 + (long)s0*16;
  {
    const char* src = (const char*)(h + n0*288);
    for (int c = (t>>6); c < 72; c += 4)
      gload_lds(src + c*1024 + (t&63)*16, (char*)tile + c*1024);
  }
  __syncthreads();
  for (int o = t; o < 288; o += 256){
    float mx[8];
    #pragma unroll
    for (int sl=0; sl<8; sl++){
      float m = -1e30f;
      #pragma unroll
      for (int kk=0; kk<16; kk++)
        m = fmaxf(m, __bfloat162float(tile[(sl*16 + kk)*288 + o]));
      mx[sl] = m;
    }
    const long e0 = OFF_FEAT + (long)b*73728 + (long)o*256 + s0;
    if (isb){
      unsigned short u[8];
      #pragma unroll
      for (int sl=0; sl<8; sl++){
        __hip_bfloat16 hb = __float2bfloat16(mx[sl]);
        __builtin_memcpy(&u[sl], &hb, 2);
      }
      uint4 pk; __builtin_memcpy(&pk, u, 16);
      *(uint4*)((__hip_bfloat16*)dout + e0) = pk;
    } else {
      float* fo = (float*)dout + e0;
      *(float4*)fo     = make_float4(mx[0],mx[1],mx[2],mx[3]);
      *(float4*)(fo+4) = make_float4(mx[4],mx[5],mx[6],mx[7]);
    }
  }
}

extern "C" void kernel_launch(void* const* d_in, const int* in_sizes, int n_in,
                              void* d_out, int out_size, void* d_ws, size_t ws_size,
                              hipStream_t stream){
  const void* xyz  = d_in[0];
  const void* feat = d_in[1];
  const void* W0 = d_in[2];  const void* g0 = d_in[3];  const void* b0 = d_in[4];
  const void* m0 = d_in[5];  const void* v0 = d_in[6];
  const void* W1 = d_in[7];  const void* g1 = d_in[8];  const void* b1 = d_in[9];
  const void* m1 = d_in[10]; const void* v1 = d_in[11];
  const void* W2 = d_in[12]; const void* g2 = d_in[13]; const void* b2 = d_in[14];
  const void* m2 = d_in[15]; const void* v2 = d_in[16];

  char* ws = (char*)d_ws;
  int*   flag  = (int*)ws;                                   // [0,64)
  float* sc0   = (float*)(ws + 64);                          // 3x(288+288) f32
  float* sh0   = sc0 + 288;
  float* sc1   = sc0 + 576;  float* sh1 = sc0 + 864;
  float* sc2   = sc0 + 1152; float* sh2 = sc0 + 1440;
  __hip_bfloat16* Wb0 = (__hip_bfloat16*)(ws + 7040);        // 288*296*2 = 170496
  __hip_bfloat16* Wb1 = Wb0 + 288*296;
  __hip_bfloat16* Wb2 = Wb1 + 288*296;                       // ends @ 518528
  float* nxyz = (float*)(ws + 518656);                       // 49152 -> 567808
  int*   bidx = (int*)(ws + 567808);                         // 262144 -> 829952
  float* X    = (float*)(ws + 1048576);                      // overlaid with bufA (dead after ballq)
  float* Y    = X + NBAT*NPT;
  float* Z    = Y + NBAT*NPT;
  __hip_bfloat16* bufA = (__hip_bfloat16*)(ws + 1048576);    // [65536][296] = 38797312
  __hip_bfloat16* bufB = (__hip_bfloat16*)(ws + 1048576 + 38797312); // [65536][288] -> end 77594624

  detect_k<<<1, 256, 0, stream>>>(xyz, flag);
  cvtxyz_k<<<3072, 256, 0, stream>>>(xyz, flag, X, Y, Z);
  cvtw_k<<<333, 256, 0, stream>>>(W0, g0, b0, m0, v0, flag, Wb0, sc0, sh0, 291);
  cvtw_k<<<333, 256, 0, stream>>>(W1, g1, b1, m1, v1, flag, Wb1, sc1, sh1, 288);
  cvtw_k<<<333, 256, 0, stream>>>(W2, g2, b2, m2, v2, flag, Wb2, sc2, sh2, 288);
  fps_k<<<NBAT, 512, 0, stream>>>(X, Y, Z, flag, nxyz, d_out);
  ballq_k<<<1024, 256, 0, stream>>>(X, Y, Z, nxyz, bidx);
  gather_k<<<1024, 256, 0, stream>>>(xyz, feat, flag, bidx, nxyz, bufA);
  gemm_k<<<dim3(512,3), 256, 128*296*2, stream>>>(bufA, 296, Wb0, sc0, sh0, bufB, 288, 10, 296);
  gemm_k<<<dim3(512,3), 256, 128*288*2, stream>>>(bufB, 288, Wb1, sc1, sh1, bufA, 296, 9, 288);
  gemm_k<<<dim3(512,3), 256, 128*296*2, stream>>>(bufA, 296, Wb2, sc2, sh2, bufB, 288, 9, 288);
  maxk_k<<<512, 256, 0, stream>>>(bufB, flag, d_out);
}